// Round 2
// baseline (319.416 us; speedup 1.0000x reference)
//
#include <hip/hip_runtime.h>

#define INF 1e10f
#define EPSV 1e-5f
#define NB 2
#define NN 512
#define NF 64
#define NH 64
#define NCC 32
#define NRBF 50
#define NND (NB*NN)

__device__ __forceinline__ float frcp(float x){ return __builtin_amdgcn_rcpf(x); }
__device__ __forceinline__ float silu_f(float x){ return x * frcp(1.f + __expf(-x)); }
__device__ __forceinline__ float tanh_f(float x){
  float cx = fminf(fmaxf(x, -15.f), 15.f);
  float t = __expf(2.f * cx);
  return (t - 1.f) * frcp(t + 1.f);
}

__device__ __forceinline__ float wredMax(float v){
  v = fmaxf(v, __shfl_down(v, 32)); v = fmaxf(v, __shfl_down(v, 16));
  v = fmaxf(v, __shfl_down(v, 8));  v = fmaxf(v, __shfl_down(v, 4));
  v = fmaxf(v, __shfl_down(v, 2));  v = fmaxf(v, __shfl_down(v, 1));
  return v;
}
__device__ __forceinline__ float wredSum(float v){
  v += __shfl_down(v, 32); v += __shfl_down(v, 16); v += __shfl_down(v, 8);
  v += __shfl_down(v, 4);  v += __shfl_down(v, 2);  v += __shfl_down(v, 1);
  return v;
}
__device__ __forceinline__ float bredMax(float v, float* red, int tid){
  float w = wredMax(v);
  __syncthreads();
  if ((tid & 63) == 0) red[tid >> 6] = w;
  __syncthreads();
  return fmaxf(fmaxf(red[0], red[1]), fmaxf(red[2], red[3]));
}
__device__ __forceinline__ float bredSum(float v, float* red, int tid){
  float w = wredSum(v);
  __syncthreads();
  if ((tid & 63) == 0) red[tid >> 6] = w;
  __syncthreads();
  return (red[0] + red[1]) + (red[2] + red[3]);
}

// ---------------- Kernel P: weight transposes (tiny, once) ----------------
// Wc1T[k][h] = Wcm1[h][k];  We3T[nc][h] = Wew[(2F+h)][nc]
__global__ void kP(const float* __restrict__ Wcm1, const float* __restrict__ Wew,
                   float* __restrict__ Wc1T, float* __restrict__ We3T){
  int t = threadIdx.x + blockIdx.x * 256;
  if (t < 4096){ int k = t >> 6, hh = t & 63; Wc1T[t] = Wcm1[hh * NH + k]; }
  if (t < 2048){ int nc = t >> 6, hh = t & 63; We3T[t] = Wew[(2 * NF + hh) * NCC + nc]; }
}

// ---------------- Kernel A: per-node projections (transposed outputs) ----
__global__ void kA(const float* __restrict__ h, const float* __restrict__ Wdh,
                   const float* __restrict__ Wew, const float* __restrict__ Wsa,
                   const float* __restrict__ bdh, const float* __restrict__ bew,
                   float* __restrict__ uT, float* __restrict__ vb,
                   float* __restrict__ e1T, float* __restrict__ e2c,
                   float* __restrict__ s1, float* __restrict__ s2){
  const int node = blockIdx.x;
  const int l = threadIdx.x;
  __shared__ float sh[NF];
  sh[l] = h[node * NF + l];
  __syncthreads();
  float ua = 0.f, va = 0.f;
  #pragma unroll
  for (int f = 0; f < NF; ++f){
    float hv = sh[f];
    ua = fmaf(hv, Wdh[f * NH + l], ua);
    va = fmaf(hv, Wdh[(NF + f) * NH + l], va);
  }
  uT[l * NND + node] = ua;                    // transposed: [h][node]
  vb[node * NH + l] = va + bdh[l];            // v + b_dh folded
  const int nc = l & 31;
  const int half = l >> 5;
  float ea = 0.f;
  #pragma unroll
  for (int f = 0; f < NF; ++f) ea = fmaf(sh[f], Wew[(half * NF + f) * NCC + nc], ea);
  if (half == 0) e1T[nc * NND + node] = ea;   // transposed: [nc][node]
  else           e2c[node * NCC + nc] = ea + bew[nc];   // + bias folded
  if (l < 2){
    const float* wp = Wsa + l * NF;
    float s = 0.f;
    #pragma unroll
    for (int f = 0; f < NF; ++f) s = fmaf(sh[f], wp[f], s);
    if (l == 0) s1[node] = s; else s2[node] = s;
  }
}

// ---------------- Kernel B: per-(b,i) edge pass, j-per-lane ---------------
__global__ __launch_bounds__(256, 3) void kB(
    const float* __restrict__ x, const float* __restrict__ mask, const float* __restrict__ mu,
    const float* __restrict__ Wf, const float* __restrict__ bf,
    const float* __restrict__ Wc1T, const float* __restrict__ bc1,
    const float* __restrict__ Wc2, const float* __restrict__ bc2,
    const float* __restrict__ We3T,
    const float* __restrict__ uT, const float* __restrict__ vb,
    const float* __restrict__ s1g, const float* __restrict__ s2g,
    const float* __restrict__ e1T, const float* __restrict__ e2c,
    float* __restrict__ hga, float* __restrict__ attn, float* __restrict__ out)
{
  const int bid = blockIdx.x;
  const int b = bid >> 9;
  const int i = bid & (NN - 1);
  const int tid = threadIdx.x;
  const int lane = tid & 63;
  const int wave = tid >> 6;
  const int base = b * NN;

  __shared__ __align__(16) float4 s_geo[NN];   // d0,d1,d2,norm        8 KB
  __shared__ __align__(16) float4 s_c[NN];     // c0,c1,c2,tot*m       8 KB
  __shared__ float s_m[NN];                    //                      2 KB
  __shared__ float s_red[4];
  __shared__ float s_fh[4][64 * 33];           // per-wave bounce   33 KB

  const float xi0 = x[(base + i) * 3 + 0];
  const float xi1 = x[(base + i) * 3 + 1];
  const float xi2 = x[(base + i) * 3 + 2];
  const float s2i = s2g[base + i];

  // ---- pass 1: logits + 3-stage softmax chain (thread-per-j, 2 j each) ----
  float aj[2], sl[2], mj[2];
  #pragma unroll
  for (int q = 0; q < 2; ++q){
    const int j = tid + q * 256;
    float d0 = x[(base + j) * 3 + 0] - xi0;
    float d1 = x[(base + j) * 3 + 1] - xi1;
    float d2 = x[(base + j) * 3 + 2] - xi2;
    float nsq = d0 * d0 + d1 * d1 + d2 * d2;
    float norm = sqrtf(fmaxf(nsq, 0.f) + EPSV);
    float m = mask[(base + i) * NN + j];
    float eye = (j == i) ? 1.f : 0.f;
    float a = -(norm + eye * INF + (1.f - m) * INF);
    float sp = s1g[base + j] + s2i;
    float sv = silu_f(sp) - eye * INF + (m - 1.f) * INF;
    s_geo[j] = make_float4(d0, d1, d2, norm);
    s_m[j] = m;
    float inv = frcp(norm * norm + EPSV) * m;
    s_c[j] = make_float4(d0 * inv, d1 * inv, d2 * inv, 0.f);
    aj[q] = a; sl[q] = sv; mj[q] = m;
  }
  float M1 = bredMax(fmaxf(aj[0], aj[1]), s_red, tid);
  float S1 = bredSum(__expf(aj[0] - M1) + __expf(aj[1] - M1), s_red, tid);
  float M2 = bredMax(fmaxf(sl[0], sl[1]), s_red, tid);
  float S2 = bredSum(__expf(sl[0] - M2) + __expf(sl[1] - M2), s_red, tid);
  const float iS1 = 1.f / S1, iS2 = 1.f / S2;
  float p[2];
  #pragma unroll
  for (int q = 0; q < 2; ++q)
    p[q] = (__expf(sl[q] - M2) * iS2) * (__expf(aj[q] - M1) * iS1) + (mj[q] - 1.f) * INF;
  float M3 = bredMax(fmaxf(p[0], p[1]), s_red, tid);
  float S3 = bredSum(__expf(p[0] - M3) + __expf(p[1] - M3), s_red, tid);
  const float iS3 = 1.f / S3;
  s_c[tid].w       = __expf(p[0] - M3) * iS3 * mj[0];    // tot*m
  s_c[tid + 256].w = __expf(p[1] - M3) * iS3 * mj[1];
  __syncthreads();

  // ---- pass 2: j-per-lane edge loop (2 groups of 64 edges per wave) ----
  const float* vbp = vb + (base + i) * NH;     // uniform -> scalar loads
  const float* e2p = e2c + (base + i) * NCC;   // uniform -> scalar loads
  const float bc2v = bc2[0];
  float* myfh = &s_fh[wave][0];

  float xa0 = 0.f, xa1 = 0.f, xa2 = 0.f;
  float at0 = 0.f, at1 = 0.f, at2 = 0.f;
  float ag0 = 0.f, ag1 = 0.f;

  for (int g = 0; g < 2; ++g){
    const int jbase = wave * 128 + g * 64;
    const int j = jbase + lane;
    float4 geo = s_geo[j];
    float m = s_m[j];
    float nrm = geo.w;

    // -- continuous-filter: fH[h] = (u[j][h]+v[i][h]+bdh[h]) * (rbf@Wf + bf)[h]
    float fH[64];
    #pragma unroll
    for (int hh = 0; hh < 64; ++hh) fH[hh] = bf[hh];
    #pragma unroll 2
    for (int r = 0; r < NRBF; ++r){
      float d = nrm - mu[r];
      float e = __expf(-10.f * d * d);
      #pragma unroll
      for (int hh = 0; hh < 64; ++hh) fH[hh] = fmaf(e, Wf[r * NH + hh], fH[hh]);
    }
    #pragma unroll
    for (int hh = 0; hh < 64; ++hh){
      float uval = uT[hh * NND + base + j];     // coalesced (lanes = consecutive j)
      fH[hh] = (uval + vbp[hh]) * fH[hh];
    }

    // -- coordinate MLP: hE = (sum_k silu(m*cm_k + bc1_k)*Wc2_k + bc2)*m
    float pv = 0.f;
    #pragma unroll 2
    for (int k = 0; k < 64; ++k){
      const float* wr = Wc1T + k * 64;          // uniform row -> s_load_dwordx16
      float a0 = 0.f, a1 = 0.f;
      #pragma unroll
      for (int c = 0; c < 32; ++c){
        a0 = fmaf(fH[c],      wr[c],      a0);
        a1 = fmaf(fH[32 + c], wr[32 + c], a1);
      }
      float t = silu_f(fmaf(m, a0 + a1, bc1[k]));
      pv = fmaf(t, Wc2[k], pv);
    }
    float hE = (pv + bc2v) * m;
    xa0 = fmaf(geo.x, hE, xa0); xa1 = fmaf(geo.y, hE, xa1); xa2 = fmaf(geo.z, hE, xa2);

    // -- edge weights: wv[nc] = tanh(e1[j][nc]+e2c[i][nc] + fH . We3T[nc]) -> LDS
    #pragma unroll 2
    for (int nc = 0; nc < NCC; ++nc){
      const float* wr = We3T + nc * 64;         // uniform row -> s_load_dwordx16
      float a0 = 0.f, a1 = 0.f;
      #pragma unroll
      for (int c = 0; c < 32; ++c){
        a0 = fmaf(fH[c],      wr[c],      a0);
        a1 = fmaf(fH[32 + c], wr[32 + c], a1);
      }
      float e1v = e1T[nc * NND + base + j];     // coalesced
      float wv = tanh_f(a0 + a1 + e1v + e2p[nc]);
      myfh[lane * 33 + nc] = wv;
    }
    asm volatile("s_waitcnt lgkmcnt(0)" ::: "memory");
    __builtin_amdgcn_wave_barrier();

    // -- att accumulation: lane -> nc=(lane&31), half-rows split across wave
    {
      const int nc = lane & 31;
      const int rb = (lane >> 5) * 32;
      for (int jj = 0; jj < 32; ++jj){
        int row = rb + jj;
        float wv = myfh[row * 33 + nc];
        float4 cc = s_c[jbase + row];
        at0 = fmaf(wv, cc.x, at0);
        at1 = fmaf(wv, cc.y, at1);
        at2 = fmaf(wv, cc.z, at2);
      }
    }
    __builtin_amdgcn_wave_barrier();

    // -- h_e_agg accumulation: bounce fH halves through LDS
    {
      #pragma unroll
      for (int c = 0; c < 32; ++c) myfh[lane * 33 + c] = fH[c];
      asm volatile("s_waitcnt lgkmcnt(0)" ::: "memory");
      __builtin_amdgcn_wave_barrier();
      const int hh = lane & 31; const int rb = (lane >> 5) * 32;
      float acc = 0.f;
      for (int jj = 0; jj < 32; ++jj){
        int row = rb + jj;
        acc = fmaf(s_c[jbase + row].w, myfh[row * 33 + hh], acc);
      }
      ag0 += acc;
      asm volatile("s_waitcnt lgkmcnt(0)" ::: "memory");
      __builtin_amdgcn_wave_barrier();
      #pragma unroll
      for (int c = 0; c < 32; ++c) myfh[lane * 33 + c] = fH[32 + c];
      asm volatile("s_waitcnt lgkmcnt(0)" ::: "memory");
      __builtin_amdgcn_wave_barrier();
      acc = 0.f;
      for (int jj = 0; jj < 32; ++jj){
        int row = rb + jj;
        acc = fmaf(s_c[jbase + row].w, myfh[row * 33 + hh], acc);
      }
      ag1 += acc;
      asm volatile("s_waitcnt lgkmcnt(0)" ::: "memory");
      __builtin_amdgcn_wave_barrier();
    }
  }

  // ---- epilogue: combine across lanes and waves ----
  float rx0 = wredSum(xa0), rx1 = wredSum(xa1), rx2 = wredSum(xa2);
  at0 += __shfl_xor(at0, 32); at1 += __shfl_xor(at1, 32); at2 += __shfl_xor(at2, 32);
  ag0 += __shfl_xor(ag0, 32); ag1 += __shfl_xor(ag1, 32);
  __syncthreads();                     // all group-phase LDS use done; alias s_fh
  float* epi   = &s_fh[0][0];
  float* s_att = epi;                  // [4][96]
  float* s_agg = epi + 384;            // [4][64]
  float* s_xw  = epi + 640;            // [4][3]
  if (lane < 32){
    s_att[wave * 96 + lane * 3 + 0] = at0;
    s_att[wave * 96 + lane * 3 + 1] = at1;
    s_att[wave * 96 + lane * 3 + 2] = at2;
    s_agg[wave * 64 + lane]      = ag0;
    s_agg[wave * 64 + 32 + lane] = ag1;
  }
  if (lane == 0){ s_xw[wave * 3 + 0] = rx0; s_xw[wave * 3 + 1] = rx1; s_xw[wave * 3 + 2] = rx2; }
  __syncthreads();
  if (tid < 96){
    float a = s_att[tid] + s_att[96 + tid] + s_att[192 + tid] + s_att[288 + tid];
    s_att[tid] = a;
  }
  if (tid >= 128 && tid < 192){
    int hh = tid - 128;
    hga[(base + i) * NH + hh] = s_agg[hh] + s_agg[64 + hh] + s_agg[128 + hh] + s_agg[192 + hh];
  }
  if (tid >= 224 && tid < 227){
    int d = tid - 224;
    out[NB * NN * NH + (base + i) * 3 + d] =
        s_xw[d] + s_xw[3 + d] + s_xw[6 + d] + s_xw[9 + d] + x[(base + i) * 3 + d];
  }
  __syncthreads();
  if (tid < 32){
    float a0 = s_att[tid * 3 + 0], a1 = s_att[tid * 3 + 1], a2 = s_att[tid * 3 + 2];
    attn[(base + i) * NCC + tid] = sqrtf(fmaxf(a0 * a0 + a1 * a1 + a2 * a2, 0.f) + EPSV);
  }
}

// ---------------- Kernel C: per-node tail MLPs ----------------------------
__global__ void kC(const float* __restrict__ h, const float* __restrict__ attn,
                   const float* __restrict__ hga,
                   const float* __restrict__ Wpn1, const float* __restrict__ bpn1,
                   const float* __restrict__ Wpn2, const float* __restrict__ bpn2,
                   const float* __restrict__ Wnm1, const float* __restrict__ bnm1,
                   const float* __restrict__ Wnm2, const float* __restrict__ bnm2,
                   float* __restrict__ out)
{
  const int node = blockIdx.x;
  const int k = threadIdx.x;
  __shared__ float sa[NCC], shh[NF], sg[NH], sq[NH], se[NH], sr[NH];
  if (k < NCC) sa[k] = attn[node * NCC + k];
  shh[k] = h[node * NF + k];
  sg[k]  = hga[node * NH + k];
  __syncthreads();
  float acc = bpn1[k];
  #pragma unroll
  for (int t = 0; t < NCC; ++t) acc = fmaf(sa[t], Wpn1[t * NH + k], acc);
  sq[k] = silu_f(acc);
  __syncthreads();
  acc = bpn2[k];
  #pragma unroll
  for (int t = 0; t < NH; ++t) acc = fmaf(sq[t], Wpn2[t * NH + k], acc);
  se[k] = acc;
  __syncthreads();
  acc = bnm1[k];
  #pragma unroll
  for (int t = 0; t < NF; ++t) acc = fmaf(shh[t], Wnm1[t * NH + k], acc);
  #pragma unroll
  for (int t = 0; t < NH; ++t) acc = fmaf(sg[t],  Wnm1[(NF + t) * NH + k], acc);
  #pragma unroll
  for (int t = 0; t < NH; ++t) acc = fmaf(se[t],  Wnm1[(NF + NH + t) * NH + k], acc);
  sr[k] = silu_f(acc);
  __syncthreads();
  acc = bnm2[k];
  #pragma unroll
  for (int t = 0; t < NH; ++t) acc = fmaf(sr[t], Wnm2[t * NH + k], acc);
  out[node * NH + k] = acc;
}

extern "C" void kernel_launch(void* const* d_in, const int* in_sizes, int n_in,
                              void* d_out, int out_size, void* d_ws, size_t ws_size,
                              hipStream_t stream){
  const float* h    = (const float*)d_in[0];
  const float* x    = (const float*)d_in[1];
  const float* mask = (const float*)d_in[2];
  const float* Wdh  = (const float*)d_in[3];
  const float* bdh  = (const float*)d_in[4];
  const float* mu   = (const float*)d_in[5];
  const float* Wf   = (const float*)d_in[6];
  const float* bf   = (const float*)d_in[7];
  const float* Wsa  = (const float*)d_in[8];
  const float* Wew  = (const float*)d_in[9];
  const float* bew  = (const float*)d_in[10];
  const float* Wpn1 = (const float*)d_in[11];
  const float* bpn1 = (const float*)d_in[12];
  const float* Wpn2 = (const float*)d_in[13];
  const float* bpn2 = (const float*)d_in[14];
  const float* Wnm1 = (const float*)d_in[15];
  const float* bnm1 = (const float*)d_in[16];
  const float* Wnm2 = (const float*)d_in[17];
  const float* bnm2 = (const float*)d_in[18];
  const float* Wcm1 = (const float*)d_in[19];
  const float* bcm1 = (const float*)d_in[20];
  const float* Wcm2 = (const float*)d_in[21];
  const float* bcm2 = (const float*)d_in[22];
  float* out = (float*)d_out;
  float* ws  = (float*)d_ws;

  float* uT   = ws;             // [64][1024]
  float* vbuf = uT   + 65536;   // [1024][64]
  float* s1   = vbuf + 65536;   // [1024]
  float* s2   = s1   + 1024;    // [1024]
  float* e1T  = s2   + 1024;    // [32][1024]
  float* e2c  = e1T  + 32768;   // [1024][32]
  float* hga  = e2c  + 32768;   // [1024][64]
  float* attn = hga  + 65536;   // [1024][32]
  float* Wc1T = attn + 32768;   // [64][64]
  float* We3T = Wc1T + 4096;    // [32][64]

  hipLaunchKernelGGL(kP, dim3(16), dim3(256), 0, stream, Wcm1, Wew, Wc1T, We3T);
  hipLaunchKernelGGL(kA, dim3(NND), dim3(64), 0, stream,
                     h, Wdh, Wew, Wsa, bdh, bew, uT, vbuf, e1T, e2c, s1, s2);
  hipLaunchKernelGGL(kB, dim3(NND), dim3(256), 0, stream,
                     x, mask, mu, Wf, bf, Wc1T, bcm1, Wcm2, bcm2, We3T,
                     uT, vbuf, s1, s2, e1T, e2c, hga, attn, out);
  hipLaunchKernelGGL(kC, dim3(NND), dim3(64), 0, stream,
                     h, attn, hga, Wpn1, bpn1, Wpn2, bpn2, Wnm1, bnm1, Wnm2, bnm2, out);
}

// Round 3
// 66.897 us; speedup vs baseline: 4.7748x; 4.7748x over previous
//
#include <hip/hip_runtime.h>

#define INF 1e10f
#define EPSV 1e-5f
#define NB 2
#define NN 512
#define NF 64
#define NH 64
#define NCC 32
#define NRBF 50
#define NND (NB*NN)
#define MU_STEP (5.0f/49.0f)

typedef _Float16 half8 __attribute__((ext_vector_type(8)));
typedef float f32x4 __attribute__((ext_vector_type(4)));

__device__ __forceinline__ float frcp(float x){ return __builtin_amdgcn_rcpf(x); }
__device__ __forceinline__ float silu_f(float x){ return x * frcp(1.f + __expf(-x)); }
__device__ __forceinline__ float tanh_f(float x){
  float cx = fminf(fmaxf(x, -15.f), 15.f);
  float t = __expf(2.f * cx);
  return (t - 1.f) * frcp(t + 1.f);
}

__device__ __forceinline__ float wredMax(float v){
  v = fmaxf(v, __shfl_down(v, 32)); v = fmaxf(v, __shfl_down(v, 16));
  v = fmaxf(v, __shfl_down(v, 8));  v = fmaxf(v, __shfl_down(v, 4));
  v = fmaxf(v, __shfl_down(v, 2));  v = fmaxf(v, __shfl_down(v, 1));
  return v;
}
__device__ __forceinline__ float wredSum(float v){
  v += __shfl_down(v, 32); v += __shfl_down(v, 16); v += __shfl_down(v, 8);
  v += __shfl_down(v, 4);  v += __shfl_down(v, 2);  v += __shfl_down(v, 1);
  return v;
}
__device__ __forceinline__ float bredMax(float v, float* red, int tid){
  float w = wredMax(v);
  __syncthreads();
  if ((tid & 63) == 0) red[tid >> 6] = w;
  __syncthreads();
  return fmaxf(fmaxf(red[0], red[1]), fmaxf(red[2], red[3]));
}
__device__ __forceinline__ float bredSum(float v, float* red, int tid){
  float w = wredSum(v);
  __syncthreads();
  if ((tid & 63) == 0) red[tid >> 6] = w;
  __syncthreads();
  return (red[0] + red[1]) + (red[2] + red[3]);
}

// -------- Kernel P: pack B-fragments (fp16, MFMA frag-linear) -------------
// frag layout: [fi][lane][4 dwords] ; fi 0..7 Wf(+bf row), 8..15 Wc1, 16..19 We3
__global__ void kP(const float* __restrict__ Wf, const float* __restrict__ bf,
                   const float* __restrict__ Wcm1, const float* __restrict__ Wew,
                   unsigned int* __restrict__ frag){
  const int fi = blockIdx.x;
  const int t = threadIdx.x;
  const int lane = t >> 2, dw = t & 3;
  float v[2];
  #pragma unroll
  for (int e2 = 0; e2 < 2; ++e2){
    int e = dw * 2 + e2;
    int kk = 8 * (lane >> 4) + e;
    int n16 = lane & 15;
    float val;
    if (fi < 8){
      int kc = fi >> 2, nt = fi & 3;
      int r = kk + 32 * kc, hcol = n16 + 16 * nt;
      val = (r < NRBF) ? Wf[r * NH + hcol] : ((r == NRBF) ? bf[hcol] : 0.f);
    } else if (fi < 16){
      int q = fi - 8; int kc = q >> 2, nt = q & 3;
      int hrow = kk + 32 * kc, kcol = n16 + 16 * nt;
      val = Wcm1[hrow * NH + kcol];
    } else {
      int q = fi - 16; int kc = q >> 1, nt = q & 1;
      int hrow = kk + 32 * kc, nc = n16 + 16 * nt;
      val = Wew[(2 * NF + hrow) * NCC + nc];
    }
    v[e2] = val;
  }
  unsigned int lo = (unsigned int)__builtin_bit_cast(unsigned short, (_Float16)v[0]);
  unsigned int hi = (unsigned int)__builtin_bit_cast(unsigned short, (_Float16)v[1]);
  frag[fi * 256 + lane * 4 + dw] = lo | (hi << 16);
}

// -------- Kernel A: per-node projections ----------------------------------
__global__ void kA(const float* __restrict__ h, const float* __restrict__ Wdh,
                   const float* __restrict__ Wew, const float* __restrict__ Wsa,
                   const float* __restrict__ bdh, const float* __restrict__ bew,
                   float* __restrict__ u, float* __restrict__ vb,
                   float* __restrict__ e1r, float* __restrict__ e2c,
                   float* __restrict__ s1, float* __restrict__ s2){
  const int node = blockIdx.x;
  const int l = threadIdx.x;
  __shared__ float sh[NF];
  sh[l] = h[node * NF + l];
  __syncthreads();
  float ua = 0.f, va = 0.f;
  #pragma unroll
  for (int f = 0; f < NF; ++f){
    float hv = sh[f];
    ua = fmaf(hv, Wdh[f * NH + l], ua);
    va = fmaf(hv, Wdh[(NF + f) * NH + l], va);
  }
  u[node * NH + l] = ua;                      // row-major [node][h]
  vb[node * NH + l] = va + bdh[l];            // + b_dh folded
  const int nc = l & 31;
  const int half = l >> 5;
  float ea = 0.f;
  #pragma unroll
  for (int f = 0; f < NF; ++f) ea = fmaf(sh[f], Wew[(half * NF + f) * NCC + nc], ea);
  if (half == 0) e1r[node * NCC + nc] = ea;   // row-major [node][nc]
  else           e2c[node * NCC + nc] = ea + bew[nc];
  if (l < 2){
    const float* wp = Wsa + l * NF;
    float s = 0.f;
    #pragma unroll
    for (int f = 0; f < NF; ++f) s = fmaf(sh[f], wp[f], s);
    if (l == 0) s1[node] = s; else s2[node] = s;
  }
}

// -------- Kernel B: per-(b,i) edge pass, MFMA core ------------------------
__global__ __launch_bounds__(256, 2) void kB(
    const float* __restrict__ x, const float* __restrict__ mask,
    const float* __restrict__ u, const float* __restrict__ vb,
    const float* __restrict__ s1g, const float* __restrict__ s2g,
    const float* __restrict__ e1r, const float* __restrict__ e2c,
    const float* __restrict__ Wc2, const float* __restrict__ bc1, const float* __restrict__ bc2g,
    const unsigned int* __restrict__ frag,
    float* __restrict__ hga, float* __restrict__ attn, float* __restrict__ out)
{
  const int bid = blockIdx.x;
  const int b = bid >> 9, i = bid & (NN - 1);
  const int tid = threadIdx.x;
  const int lane = tid & 63, wave = tid >> 6;
  const int l15 = lane & 15, g = lane >> 4;
  const int base = b * NN;

  __shared__ __align__(16) float4 s_geo[NN];     // d0,d1,d2,norm   8KB
  __shared__ __align__(16) float4 s_c[NN];       // c0,c1,c2,tot*m  8KB
  __shared__ float s_m[NN];                      // 2KB
  __shared__ float s_red[4];
  __shared__ half8 s_WB[16][64];                 // Wf(0..7)+Wc1(8..15) frags 16KB
  __shared__ float s_filt[4][1088];              // per-wave [64h][17] 17KB

  // stage Wf+Wc1 B-frags into LDS (1024 int4)
  {
    const int4* src = (const int4*)frag;
    int4* dst = (int4*)&s_WB[0][0];
    #pragma unroll
    for (int q = 0; q < 4; ++q) dst[tid + q * 256] = src[tid + q * 256];
  }
  // We3 frags to registers
  half8 we3[4];
  {
    const int4* src = (const int4*)frag;
    #pragma unroll
    for (int q = 0; q < 4; ++q)
      we3[q] = __builtin_bit_cast(half8, src[(16 + q) * 64 + lane]);
  }

  const float xi0 = x[(base + i) * 3 + 0];
  const float xi1 = x[(base + i) * 3 + 1];
  const float xi2 = x[(base + i) * 3 + 2];
  const float s2i = s2g[base + i];

  // ---- pass 1: logits + 3-stage softmax chain ----
  float aj[2], sl[2], mj[2];
  #pragma unroll
  for (int q = 0; q < 2; ++q){
    const int j = tid + q * 256;
    float d0 = x[(base + j) * 3 + 0] - xi0;
    float d1 = x[(base + j) * 3 + 1] - xi1;
    float d2 = x[(base + j) * 3 + 2] - xi2;
    float nsq = d0 * d0 + d1 * d1 + d2 * d2;
    float norm = sqrtf(fmaxf(nsq, 0.f) + EPSV);
    float m = mask[(base + i) * NN + j];
    float eye = (j == i) ? 1.f : 0.f;
    float a = -(norm + eye * INF + (1.f - m) * INF);
    float sp = s1g[base + j] + s2i;
    float sv = silu_f(sp) - eye * INF + (m - 1.f) * INF;
    s_geo[j] = make_float4(d0, d1, d2, norm);
    s_m[j] = m;
    float inv = frcp(norm * norm + EPSV) * m;
    s_c[j] = make_float4(d0 * inv, d1 * inv, d2 * inv, 0.f);
    aj[q] = a; sl[q] = sv; mj[q] = m;
  }
  float M1 = bredMax(fmaxf(aj[0], aj[1]), s_red, tid);
  float S1 = bredSum(__expf(aj[0] - M1) + __expf(aj[1] - M1), s_red, tid);
  float M2 = bredMax(fmaxf(sl[0], sl[1]), s_red, tid);
  float S2 = bredSum(__expf(sl[0] - M2) + __expf(sl[1] - M2), s_red, tid);
  const float iS1 = 1.f / S1, iS2 = 1.f / S2;
  float p[2];
  #pragma unroll
  for (int q = 0; q < 2; ++q)
    p[q] = (__expf(sl[q] - M2) * iS2) * (__expf(aj[q] - M1) * iS1) + (mj[q] - 1.f) * INF;
  float M3 = bredMax(fmaxf(p[0], p[1]), s_red, tid);
  float S3 = bredSum(__expf(p[0] - M3) + __expf(p[1] - M3), s_red, tid);
  const float iS3 = 1.f / S3;
  s_c[tid].w       = __expf(p[0] - M3) * iS3 * mj[0];
  s_c[tid + 256].w = __expf(p[1] - M3) * iS3 * mj[1];
  __syncthreads();   // covers pass-1 LDS + s_WB staging

  // ---- per-i prologue ----
  float vba[16];
  {
    const float4* vp = (const float4*)(vb + (size_t)(base + i) * NH);
    float4 a0 = vp[2*g], a1 = vp[2*g+1], a2 = vp[2*g+8], a3 = vp[2*g+9];
    vba[0]=a0.x; vba[1]=a0.y; vba[2]=a0.z; vba[3]=a0.w;
    vba[4]=a1.x; vba[5]=a1.y; vba[6]=a1.z; vba[7]=a1.w;
    vba[8]=a2.x; vba[9]=a2.y; vba[10]=a2.z; vba[11]=a2.w;
    vba[12]=a3.x; vba[13]=a3.y; vba[14]=a3.z; vba[15]=a3.w;
  }
  float wc2v[4], bc1v[4];
  #pragma unroll
  for (int nt = 0; nt < 4; ++nt){ wc2v[nt] = Wc2[l15 + 16*nt]; bc1v[nt] = bc1[l15 + 16*nt]; }
  float e2v[2];
  e2v[0] = e2c[(size_t)(base + i) * NCC + l15];
  e2v[1] = e2c[(size_t)(base + i) * NCC + l15 + 16];
  const float bc2v = bc2g[0];

  float hg[16];
  #pragma unroll
  for (int e = 0; e < 16; ++e) hg[e] = 0.f;
  float at[2][3] = {{0.f,0.f,0.f},{0.f,0.f,0.f}};
  float xa0 = 0.f, xa1 = 0.f, xa2 = 0.f;
  float* fw = &s_filt[wave][0];

  // ---- pass 2: 8 j-tiles of 16 per wave ----
  for (int jt8 = 0; jt8 < 8; ++jt8){
    const int jt = wave * 128 + jt8 * 16;
    const int jl = jt + l15;
    // early global loads
    const float4* up = (const float4*)(u + (size_t)(base + jl) * NH);
    float4 u0 = up[2*g], u1 = up[2*g+1], u2 = up[2*g+8], u3 = up[2*g+9];
    float e1v[4][2];
    #pragma unroll
    for (int reg = 0; reg < 4; ++reg){
      const float* ep1 = e1r + (size_t)(base + jt + 4*g + reg) * NCC + l15;
      e1v[reg][0] = ep1[0]; e1v[reg][1] = ep1[16];
    }
    float normj = s_geo[jl].w;
    float tmw = s_c[jl].w;
    // rbf A-frags (direct fragment-layout compute; r=50 row == bias 1.0)
    half8 arb[2];
    #pragma unroll
    for (int kc = 0; kc < 2; ++kc){
      #pragma unroll
      for (int rr = 0; rr < 8; ++rr){
        int r = 8*g + rr + 32*kc;
        float d = normj - (float)r * MU_STEP;
        float ev = __expf(-10.f * d * d);
        float val = (r < NRBF) ? ev : ((r == NRBF) ? 1.f : 0.f);
        arb[kc][rr] = (_Float16)val;
      }
    }
    // filt = rbf @ Wf(+bf)
    f32x4 fc[4];
    #pragma unroll
    for (int nt = 0; nt < 4; ++nt){
      f32x4 z = {0.f,0.f,0.f,0.f};
      z = __builtin_amdgcn_mfma_f32_16x16x32_f16(arb[0], s_WB[nt][lane], z, 0, 0, 0);
      z = __builtin_amdgcn_mfma_f32_16x16x32_f16(arb[1], s_WB[4+nt][lane], z, 0, 0, 0);
      fc[nt] = z;
    }
    // write filt transposed [h][17] (C-layout -> conflict-free)
    #pragma unroll
    for (int nt = 0; nt < 4; ++nt)
      #pragma unroll
      for (int reg = 0; reg < 4; ++reg)
        fw[(l15 + 16*nt) * 17 + 4*g + reg] = fc[nt][reg];
    __builtin_amdgcn_wave_barrier();
    asm volatile("" ::: "memory");
    // read back in A-layout, compose FH = (u + vb) * filt
    float ua[16] = {u0.x,u0.y,u0.z,u0.w, u1.x,u1.y,u1.z,u1.w,
                    u2.x,u2.y,u2.z,u2.w, u3.x,u3.y,u3.z,u3.w};
    float FH[16];
    #pragma unroll
    for (int kc = 0; kc < 2; ++kc)
      #pragma unroll
      for (int rr = 0; rr < 8; ++rr){
        int e = kc*8 + rr;
        int hh = 8*g + rr + 32*kc;
        float f = fw[hh * 17 + l15];
        FH[e] = (ua[e] + vba[e]) * f;
      }
    // hga accumulation (fp32) + fp16 A-frags
    half8 afh[2];
    #pragma unroll
    for (int e = 0; e < 16; ++e) hg[e] = fmaf(tmw, FH[e], hg[e]);
    #pragma unroll
    for (int kc = 0; kc < 2; ++kc)
      #pragma unroll
      for (int rr = 0; rr < 8; ++rr)
        afh[kc][rr] = (_Float16)FH[kc*8 + rr];
    // CM = FH @ Wc1 ; EW = FH @ We3
    f32x4 cm[4];
    #pragma unroll
    for (int nt = 0; nt < 4; ++nt){
      f32x4 z = {0.f,0.f,0.f,0.f};
      z = __builtin_amdgcn_mfma_f32_16x16x32_f16(afh[0], s_WB[8+nt][lane], z, 0, 0, 0);
      z = __builtin_amdgcn_mfma_f32_16x16x32_f16(afh[1], s_WB[12+nt][lane], z, 0, 0, 0);
      cm[nt] = z;
    }
    f32x4 ew[2];
    #pragma unroll
    for (int n2 = 0; n2 < 2; ++n2){
      f32x4 z = {0.f,0.f,0.f,0.f};
      z = __builtin_amdgcn_mfma_f32_16x16x32_f16(afh[0], we3[n2],   z, 0, 0, 0);
      z = __builtin_amdgcn_mfma_f32_16x16x32_f16(afh[1], we3[2+n2], z, 0, 0, 0);
      ew[n2] = z;
    }
    // per-reg j scalars
    float mreg[4]; float4 geo4[4], c4[4];
    #pragma unroll
    for (int reg = 0; reg < 4; ++reg){
      int jr = jt + 4*g + reg;
      mreg[reg] = s_m[jr];
      geo4[reg] = s_geo[jr];
      c4[reg]   = s_c[jr];
    }
    // coordinate MLP: silu + dot(Wc2) + 16-lane reduce -> hE
    float hEp[4] = {0.f,0.f,0.f,0.f};
    #pragma unroll
    for (int nt = 0; nt < 4; ++nt)
      #pragma unroll
      for (int reg = 0; reg < 4; ++reg){
        float tv = silu_f(fmaf(mreg[reg], cm[nt][reg], bc1v[nt]));
        hEp[reg] = fmaf(tv, wc2v[nt], hEp[reg]);
      }
    #pragma unroll
    for (int reg = 0; reg < 4; ++reg){
      float v = hEp[reg];
      v += __shfl_xor(v, 1); v += __shfl_xor(v, 2);
      v += __shfl_xor(v, 4); v += __shfl_xor(v, 8);
      float hE = (v + bc2v) * mreg[reg];
      xa0 = fmaf(geo4[reg].x, hE, xa0);
      xa1 = fmaf(geo4[reg].y, hE, xa1);
      xa2 = fmaf(geo4[reg].z, hE, xa2);
    }
    // edge weights: tanh + att accumulation
    #pragma unroll
    for (int n2 = 0; n2 < 2; ++n2)
      #pragma unroll
      for (int reg = 0; reg < 4; ++reg){
        float wv = tanh_f(ew[n2][reg] + e1v[reg][n2] + e2v[n2]);
        at[n2][0] = fmaf(wv, c4[reg].x, at[n2][0]);
        at[n2][1] = fmaf(wv, c4[reg].y, at[n2][1]);
        at[n2][2] = fmaf(wv, c4[reg].z, at[n2][2]);
      }
  }

  // ---- reduces ----
  #pragma unroll
  for (int e = 0; e < 16; ++e){
    float v = hg[e];
    v += __shfl_xor(v, 1); v += __shfl_xor(v, 2);
    v += __shfl_xor(v, 4); v += __shfl_xor(v, 8);
    hg[e] = v;
  }
  #pragma unroll
  for (int n2 = 0; n2 < 2; ++n2)
    #pragma unroll
    for (int d = 0; d < 3; ++d){
      float v = at[n2][d];
      v += __shfl_xor(v, 16); v += __shfl_xor(v, 32);
      at[n2][d] = v;
    }
  xa0 += __shfl_xor(xa0, 16); xa0 += __shfl_xor(xa0, 32);
  xa1 += __shfl_xor(xa1, 16); xa1 += __shfl_xor(xa1, 32);
  xa2 += __shfl_xor(xa2, 16); xa2 += __shfl_xor(xa2, 32);

  // ---- epilogue across waves (alias s_filt) ----
  __syncthreads();
  float* ep = &s_filt[0][0];
  if (l15 == 0){
    #pragma unroll
    for (int e = 0; e < 16; ++e)
      ep[wave*64 + 8*g + (e & 7) + 32*(e >> 3)] = hg[e];
  }
  if (lane < 16){
    #pragma unroll
    for (int n2 = 0; n2 < 2; ++n2)
      #pragma unroll
      for (int d = 0; d < 3; ++d)
        ep[256 + wave*96 + (l15 + 16*n2)*3 + d] = at[n2][d];
  }
  if (lane == 0){
    ep[640 + wave*3 + 0] = xa0; ep[640 + wave*3 + 1] = xa1; ep[640 + wave*3 + 2] = xa2;
  }
  __syncthreads();
  if (tid < 64)
    hga[(size_t)(base + i) * NH + tid] = ep[tid] + ep[64+tid] + ep[128+tid] + ep[192+tid];
  if (tid >= 64 && tid < 160){
    int t = tid - 64;
    ep[704 + t] = ep[256+t] + ep[352+t] + ep[448+t] + ep[544+t];
  }
  if (tid >= 192 && tid < 195){
    int d = tid - 192;
    out[NB*NN*NH + (base + i)*3 + d] =
        ep[640+d] + ep[643+d] + ep[646+d] + ep[649+d] + x[(base + i)*3 + d];
  }
  __syncthreads();
  if (tid < 32){
    float a0 = ep[704 + tid*3], a1 = ep[704 + tid*3 + 1], a2 = ep[704 + tid*3 + 2];
    attn[(size_t)(base + i) * NCC + tid] = sqrtf(fmaxf(a0*a0 + a1*a1 + a2*a2, 0.f) + EPSV);
  }
}

// -------- Kernel C: per-node tail MLPs ------------------------------------
__global__ void kC(const float* __restrict__ h, const float* __restrict__ attn,
                   const float* __restrict__ hga,
                   const float* __restrict__ Wpn1, const float* __restrict__ bpn1,
                   const float* __restrict__ Wpn2, const float* __restrict__ bpn2,
                   const float* __restrict__ Wnm1, const float* __restrict__ bnm1,
                   const float* __restrict__ Wnm2, const float* __restrict__ bnm2,
                   float* __restrict__ out)
{
  const int node = blockIdx.x;
  const int k = threadIdx.x;
  __shared__ float sa[NCC], shh[NF], sg[NH], sq[NH], se[NH], sr[NH];
  if (k < NCC) sa[k] = attn[node * NCC + k];
  shh[k] = h[node * NF + k];
  sg[k]  = hga[node * NH + k];
  __syncthreads();
  float acc = bpn1[k];
  #pragma unroll
  for (int t = 0; t < NCC; ++t) acc = fmaf(sa[t], Wpn1[t * NH + k], acc);
  sq[k] = silu_f(acc);
  __syncthreads();
  acc = bpn2[k];
  #pragma unroll
  for (int t = 0; t < NH; ++t) acc = fmaf(sq[t], Wpn2[t * NH + k], acc);
  se[k] = acc;
  __syncthreads();
  acc = bnm1[k];
  #pragma unroll
  for (int t = 0; t < NF; ++t) acc = fmaf(shh[t], Wnm1[t * NH + k], acc);
  #pragma unroll
  for (int t = 0; t < NH; ++t) acc = fmaf(sg[t],  Wnm1[(NF + t) * NH + k], acc);
  #pragma unroll
  for (int t = 0; t < NH; ++t) acc = fmaf(se[t],  Wnm1[(NF + NH + t) * NH + k], acc);
  sr[k] = silu_f(acc);
  __syncthreads();
  acc = bnm2[k];
  #pragma unroll
  for (int t = 0; t < NH; ++t) acc = fmaf(sr[t], Wnm2[t * NH + k], acc);
  out[node * NH + k] = acc;
}

extern "C" void kernel_launch(void* const* d_in, const int* in_sizes, int n_in,
                              void* d_out, int out_size, void* d_ws, size_t ws_size,
                              hipStream_t stream){
  const float* h    = (const float*)d_in[0];
  const float* x    = (const float*)d_in[1];
  const float* mask = (const float*)d_in[2];
  const float* Wdh  = (const float*)d_in[3];
  const float* bdh  = (const float*)d_in[4];
  const float* Wf   = (const float*)d_in[6];
  const float* bf   = (const float*)d_in[7];
  const float* Wsa  = (const float*)d_in[8];
  const float* Wew  = (const float*)d_in[9];
  const float* bew  = (const float*)d_in[10];
  const float* Wpn1 = (const float*)d_in[11];
  const float* bpn1 = (const float*)d_in[12];
  const float* Wpn2 = (const float*)d_in[13];
  const float* bpn2 = (const float*)d_in[14];
  const float* Wnm1 = (const float*)d_in[15];
  const float* bnm1 = (const float*)d_in[16];
  const float* Wnm2 = (const float*)d_in[17];
  const float* bnm2 = (const float*)d_in[18];
  const float* Wcm1 = (const float*)d_in[19];
  const float* bcm1 = (const float*)d_in[20];
  const float* Wcm2 = (const float*)d_in[21];
  const float* bcm2 = (const float*)d_in[22];
  float* out = (float*)d_out;
  float* ws  = (float*)d_ws;

  float* u    = ws;             // [1024][64]
  float* vbuf = u    + 65536;   // [1024][64]
  float* s1   = vbuf + 65536;   // [1024]
  float* s2   = s1   + 1024;    // [1024]
  float* e1r  = s2   + 1024;    // [1024][32]
  float* e2c  = e1r  + 32768;   // [1024][32]
  float* hga  = e2c  + 32768;   // [1024][64]
  float* attn = hga  + 65536;   // [1024][32]
  unsigned int* fragb = (unsigned int*)(attn + 32768);  // 20*256 u32

  hipLaunchKernelGGL(kP, dim3(20), dim3(256), 0, stream, Wf, bf, Wcm1, Wew, fragb);
  hipLaunchKernelGGL(kA, dim3(NND), dim3(64), 0, stream,
                     h, Wdh, Wew, Wsa, bdh, bew, u, vbuf, e1r, e2c, s1, s2);
  hipLaunchKernelGGL(kB, dim3(NND), dim3(256), 0, stream,
                     x, mask, u, vbuf, s1, s2, e1r, e2c, Wcm2, bcm1, bcm2,
                     fragb, hga, attn, out);
  hipLaunchKernelGGL(kC, dim3(NND), dim3(64), 0, stream,
                     h, attn, hga, Wpn1, bpn1, Wpn2, bpn2, Wnm1, bnm1, Wnm2, bnm2, out);
}